// Round 1
// baseline (535.525 us; speedup 1.0000x reference)
//
#include <hip/hip_runtime.h>

// Problem constants: B=256, C=64, T=4096, SNR_DB=10 -> 10^(-1)=0.1
// Layouts (all contiguous fp32, identical row layout):
//   x         : [B,1,C,T]  -> row r = b*C+c, offset r*T
//   noise_unit: [B,C,T]    -> same row offsets
//   out       : [B,1,C,T]  -> same
// One block per (b,c) row: 256 threads x 16 elems (4x float4) = 4096 = T.
// x row held in registers so it is fetched from HBM exactly once.
// NEW vs prev best (580.2 us):
//  - mask[b]==0 rows (≈50%, CHANCE=0.5) skip the noise_unit read, the
//    reduction and the barrier entirely: out = x bit-exactly. ~-16% HBM traffic.
//  - nontemporal load/store on all streaming data (805 MB through 256 MB L3:
//    zero reuse, avoid write-allocate pollution).

#define T_LEN 4096
#define C_CH  64
#define THREADS 256
#define ELEMS 4  // float4 chunks per thread: 4 * 4 * 256 = 4096 floats

typedef float f4 __attribute__((ext_vector_type(4)));

__global__ __launch_bounds__(THREADS) void gaussian_noise_kernel(
    const float* __restrict__ x,
    const float* __restrict__ noise_unit,
    const int* __restrict__ mask,
    float* __restrict__ out)
{
    const int row = blockIdx.x;          // b*C + c
    const int b = row >> 6;              // / C_CH (C_CH == 64)
    const long long base = (long long)row * T_LEN;

    const f4* __restrict__ x4 = (const f4*)(x + base);
    const f4* __restrict__ n4 = (const f4*)(noise_unit + base);
    f4* __restrict__ o4 = (f4*)(out + base);

    const int tid = threadIdx.x;
    const int m = mask[b];               // block-uniform

    // Load x row into registers (single HBM fetch of x, streaming hint).
    f4 xa[ELEMS];
#pragma unroll
    for (int i = 0; i < ELEMS; ++i)
        xa[i] = __builtin_nontemporal_load(&x4[tid + i * THREADS]);

    if (!m) {
        // Unmasked batch: out = x exactly (reference: where(mask, noise, 0)).
        // Skip noise read, reduction, and barrier.
#pragma unroll
        for (int i = 0; i < ELEMS; ++i)
            __builtin_nontemporal_store(xa[i], &o4[tid + i * THREADS]);
        return;
    }

    // Partial sum per thread (same order as previously-verified kernel).
    float sum = 0.0f;
#pragma unroll
    for (int i = 0; i < ELEMS; ++i)
        sum += (xa[i].x + xa[i].y) + (xa[i].z + xa[i].w);

    // Wave (64-lane) shuffle reduction.
#pragma unroll
    for (int off = 32; off > 0; off >>= 1)
        sum += __shfl_down(sum, off, 64);

    __shared__ float wsum[THREADS / 64];
    const int lane = tid & 63;
    const int wid = tid >> 6;
    if (lane == 0) wsum[wid] = sum;
    __syncthreads();

    const float tot = (wsum[0] + wsum[1]) + (wsum[2] + wsum[3]);
    const float p_sig = fabsf(tot * (1.0f / (float)T_LEN));
    const float g = sqrtf(p_sig * 0.1f);   // 10^(-SNR_DB/10) = 0.1

    // out = x + noise_unit * g
#pragma unroll
    for (int i = 0; i < ELEMS; ++i) {
        const f4 n = __builtin_nontemporal_load(&n4[tid + i * THREADS]);
        f4 o;
        o.x = fmaf(n.x, g, xa[i].x);
        o.y = fmaf(n.y, g, xa[i].y);
        o.z = fmaf(n.z, g, xa[i].z);
        o.w = fmaf(n.w, g, xa[i].w);
        __builtin_nontemporal_store(o, &o4[tid + i * THREADS]);
    }
}

extern "C" void kernel_launch(void* const* d_in, const int* in_sizes, int n_in,
                              void* d_out, int out_size, void* d_ws, size_t ws_size,
                              hipStream_t stream) {
    const float* x          = (const float*)d_in[0];
    const float* noise_unit = (const float*)d_in[1];
    const int*   mask       = (const int*)d_in[2];   // bool [B] materialized as int32
    float* out = (float*)d_out;

    const int n_rows = 256 * C_CH;  // B * C = 16384 blocks
    gaussian_noise_kernel<<<n_rows, THREADS, 0, stream>>>(x, noise_unit, mask, out);
}

// Round 2
// 534.785 us; speedup vs baseline: 1.0014x; 1.0014x over previous
//
#include <hip/hip_runtime.h>

// Problem constants: B=256, C=64, T=4096, SNR_DB=10 -> 10^(-1)=0.1
// Layouts (all contiguous fp32, identical row layout):
//   x         : [B,1,C,T]  -> row r = b*C+c, offset r*T
//   noise_unit: [B,C,T]    -> same row offsets
//   out       : [B,1,C,T]  -> same
// One block per (b,c) row: 256 threads x 16 elems (4x float4) = 4096 = T.
// x row held in registers so it is fetched from HBM exactly once.
// R1 (535.5 us): mask-gated noise skip + nontemporal hints.
// R2 change: on the masked path, prefetch ALL noise_unit loads into registers
//   BEFORE the reduction/barrier. Compiler cannot hoist global loads across
//   __syncthreads, so previously half the row's traffic only started issuing
//   after the reduce completed. Now all 32 loads are in flight together and
//   the barrier gates only the FMA+store. (+16 VGPR, no occupancy change.)

#define T_LEN 4096
#define C_CH  64
#define THREADS 256
#define ELEMS 4  // float4 chunks per thread: 4 * 4 * 256 = 4096 floats

typedef float f4 __attribute__((ext_vector_type(4)));

__global__ __launch_bounds__(THREADS) void gaussian_noise_kernel(
    const float* __restrict__ x,
    const float* __restrict__ noise_unit,
    const int* __restrict__ mask,
    float* __restrict__ out)
{
    const int row = blockIdx.x;          // b*C + c
    const int b = row >> 6;              // / C_CH (C_CH == 64)
    const long long base = (long long)row * T_LEN;

    const f4* __restrict__ x4 = (const f4*)(x + base);
    const f4* __restrict__ n4 = (const f4*)(noise_unit + base);
    f4* __restrict__ o4 = (f4*)(out + base);

    const int tid = threadIdx.x;
    const int m = mask[b];               // block-uniform

    // Load x row into registers (single HBM fetch of x, streaming hint).
    f4 xa[ELEMS];
#pragma unroll
    for (int i = 0; i < ELEMS; ++i)
        xa[i] = __builtin_nontemporal_load(&x4[tid + i * THREADS]);

    if (!m) {
        // Unmasked batch (~50%): out = x exactly (reference: where(mask, noise, 0)).
        // Pure streaming copy; skip noise read, reduction, and barrier.
#pragma unroll
        for (int i = 0; i < ELEMS; ++i)
            __builtin_nontemporal_store(xa[i], &o4[tid + i * THREADS]);
        return;
    }

    // Prefetch the noise row NOW so its HBM latency overlaps the reduction
    // and barrier below (loads cannot be hoisted across __syncthreads).
    f4 na[ELEMS];
#pragma unroll
    for (int i = 0; i < ELEMS; ++i)
        na[i] = __builtin_nontemporal_load(&n4[tid + i * THREADS]);

    // Partial sum per thread (same order as previously-verified kernel).
    float sum = 0.0f;
#pragma unroll
    for (int i = 0; i < ELEMS; ++i)
        sum += (xa[i].x + xa[i].y) + (xa[i].z + xa[i].w);

    // Wave (64-lane) shuffle reduction.
#pragma unroll
    for (int off = 32; off > 0; off >>= 1)
        sum += __shfl_down(sum, off, 64);

    __shared__ float wsum[THREADS / 64];
    const int lane = tid & 63;
    const int wid = tid >> 6;
    if (lane == 0) wsum[wid] = sum;
    __syncthreads();

    const float tot = (wsum[0] + wsum[1]) + (wsum[2] + wsum[3]);
    // g = sqrt(|mean| * 0.1); (0.1f/4096) folds the exact /2^12 into the const,
    // bit-identical to (|tot|/4096)*0.1f since /4096 is exact.
    const float g = sqrtf(fabsf(tot) * (0.1f / (float)T_LEN));

    // out = x + noise_unit * g
#pragma unroll
    for (int i = 0; i < ELEMS; ++i) {
        f4 o;
        o.x = fmaf(na[i].x, g, xa[i].x);
        o.y = fmaf(na[i].y, g, xa[i].y);
        o.z = fmaf(na[i].z, g, xa[i].z);
        o.w = fmaf(na[i].w, g, xa[i].w);
        __builtin_nontemporal_store(o, &o4[tid + i * THREADS]);
    }
}

extern "C" void kernel_launch(void* const* d_in, const int* in_sizes, int n_in,
                              void* d_out, int out_size, void* d_ws, size_t ws_size,
                              hipStream_t stream) {
    const float* x          = (const float*)d_in[0];
    const float* noise_unit = (const float*)d_in[1];
    const int*   mask       = (const int*)d_in[2];   // bool [B] materialized as int32
    float* out = (float*)d_out;

    const int n_rows = 256 * C_CH;  // B * C = 16384 blocks
    gaussian_noise_kernel<<<n_rows, THREADS, 0, stream>>>(x, noise_unit, mask, out);
}